// Round 3
// baseline (1601.575 us; speedup 1.0000x reference)
//
#include <hip/hip_runtime.h>

#define N_SEQ 250000
#define LSEQ  40
#define CIN   20
#define KW    4
#define DCH   32
#define L1    37   // LSEQ - KW + 1
#define L2    34   // L1 - KW + 1
#define N_BAGS 100
#define SPB   2500
#define NTHR  256
#define WPB   4              // waves per block, 1 sequence per wave
#define H1S   40             // h1 row stride (f16): 80 B -> every row 16B-aligned (b128 reads),
                             // rows r and r+4 land on complementary bank halves (conflict-free b16 writes)

typedef _Float16 f16;
typedef _Float16 f16x8 __attribute__((ext_vector_type(8)));
typedef _Float16 f16x4 __attribute__((ext_vector_type(4)));
typedef float    f32x16 __attribute__((ext_vector_type(16)));

__device__ __forceinline__ float selu_f(float x) {
  float e = 1.6732632423543772f * (__expf(x) - 1.0f);
  return 1.0507009873554805f * ((x > 0.0f) ? x : e);
}

__device__ __forceinline__ float lane_bcast(float v, int srclane) {
  // wave-uniform broadcast via v_readlane -> SGPR (VALU pipe, not LDS/bpermute)
  return __int_as_float(__builtin_amdgcn_readlane(__float_as_int(v), srclane));
}

// ---- prep: transpose+convert weights once per launch (1 block, ~2 us) ----
__global__ __launch_bounds__(256) void prep_kernel(
    const float* __restrict__ w1, const float* __restrict__ w2,
    const float* __restrict__ aw1, const float* __restrict__ aw2,
    f16* __restrict__ w1T, f16* __restrict__ w2T,
    float* __restrict__ aw1T, float* __restrict__ aw2T)
{
  const int tid = threadIdx.x;
  for (int i = tid; i < 32 * 80; i += 256) {
    const int n = i / 80, k = i - n * 80;
    w1T[i] = (f16)w1[k * 32 + n];
  }
  for (int i = tid; i < 32 * 128; i += 256) {
    const int n = i >> 7, k = i & 127;
    w2T[i] = (f16)w2[k * 32 + n];
  }
  for (int i = tid; i < 1024; i += 256) {
    const int d = i >> 5, c = i & 31;
    aw1T[i] = aw1[c * 32 + d];
    aw2T[i] = aw2[c * 32 + d];
  }
}

// ---- kernel 1: one sequence per wave, ZERO barriers, per-wave private LDS.
//      conv1/conv2 via 32x32x16 f16 MFMA with compile-time 2-tile unroll,
//      in-register maxpool, readlane-broadcast attention.
//      LDS 18.24 KB/block -> 8 blk/CU = 32 waves/CU (100% cap). ----
__global__ __launch_bounds__(NTHR, 4) void seq_kernel(
    const float* __restrict__ x,
    const f16*  __restrict__ w1T, const float* __restrict__ b1,
    const f16*  __restrict__ w2T, const float* __restrict__ b2,
    const float* __restrict__ aw1T, const float* __restrict__ ab1,
    const float* __restrict__ aw2T, const float* __restrict__ ab2,
    const float* __restrict__ aw3, const float* __restrict__ ab3,
    f16* __restrict__ se_out, float* __restrict__ sc_out)
{
  __shared__ __align__(16) f16 xs[WPB][LSEQ * CIN];   // 4 x 1600 B
  __shared__ __align__(16) f16 h1[WPB][L1 * H1S];     // 4 x 2960 B ; total 18240 B

  const int tid  = threadIdx.x;
  const int lane = tid & 63;
  const int wave = tid >> 6;     // 0..3 -> sequence index within block
  const int m    = lane & 31;    // MFMA A-row supplier / C,D column (channel)
  const int half = lane >> 5;    // MFMA k-half selector
  const int seq  = blockIdx.x * WPB + wave;

  f16* xw  = xs[wave];
  f16* h1w = h1[wave];

  // ---- stage this wave's sequence: 800 f32 -> 800 f16 (2x dwordx4 -> 1x b128) ----
  {
    const float4* xg = (const float4*)(x + (size_t)seq * (LSEQ * CIN));
    for (int i = lane; i < 100; i += 64) {
      const float4 v0 = xg[2 * i];
      const float4 v1 = xg[2 * i + 1];
      f16x8 h;
      h[0] = (f16)v0.x; h[1] = (f16)v0.y; h[2] = (f16)v0.z; h[3] = (f16)v0.w;
      h[4] = (f16)v1.x; h[5] = (f16)v1.y; h[6] = (f16)v1.z; h[7] = (f16)v1.w;
      *(f16x8*)&xw[i * 8] = h;
    }
  }

  // ---- conv1 B fragments (L2-hot) ----
  f16x8 bf1[5];
  {
    const f16x8* w1t8 = (const f16x8*)w1T;
    #pragma unroll
    for (int kc = 0; kc < 5; kc++) bf1[kc] = w1t8[m * 10 + kc * 2 + half];
  }
  const float b1v = b1[m];
  // no barrier: same-wave LDS RAW ordered by compiler lgkmcnt

  // ---- conv1: rows 0..36, two compile-time tiles (0..31, 32..36+pad) ----
  #pragma unroll
  for (int tile = 0; tile < 2; tile++) {
    const int l = tile ? min(32 + m, L1 - 1) : m;   // clamped lanes feed garbage rows >= 37 (never stored)
    const f16* arow = &xw[l * CIN];
    f32x16 acc;
    #pragma unroll
    for (int i = 0; i < 16; i++) acc[i] = b1v;
    #pragma unroll
    for (int kc = 0; kc < 5; kc++) {
      const int e = kc * 16 + half * 8;             // 80-elem contiguous im2col window
      const f16x4 p0 = *(const f16x4*)(arow + e);
      const f16x4 p1 = *(const f16x4*)(arow + e + 4);
      const f16x8 a = __builtin_shufflevector(p0, p1, 0, 1, 2, 3, 4, 5, 6, 7);
      acc = __builtin_amdgcn_mfma_f32_32x32x16_f16(a, bf1[kc], acc, 0, 0, 0);
    }
    if (tile == 0) {
      #pragma unroll
      for (int reg = 0; reg < 16; reg++) {
        const int rr = (reg & 3) + 8 * (reg >> 2) + 4 * half;   // compile-time per (reg,half)
        h1w[rr * H1S + m] = (f16)selu_f(acc[reg]);
      }
    } else {
      // valid rows 32..36: half0 regs 0..3 (32..35), half1 reg 0 (36) -- compile-time predication
      if (half == 0) {
        #pragma unroll
        for (int reg = 0; reg < 4; reg++)
          h1w[(32 + reg) * H1S + m] = (f16)selu_f(acc[reg]);
      } else {
        h1w[36 * H1S + m] = (f16)selu_f(acc[0]);
      }
    }
  }

  // ---- conv2 B fragments ----
  f16x8 bf2[8];
  {
    const f16x8* w2t8 = (const f16x8*)w2T;
    #pragma unroll
    for (int kc = 0; kc < 8; kc++) bf2[kc] = w2t8[m * 16 + kc * 2 + half];
  }
  const float b2v = b2[m];

  // ---- conv2: rows 0..33, two tiles; maxpool in-register (bias+selu deferred past max) ----
  float mx = -3.4e38f;
  #pragma unroll
  for (int tile = 0; tile < 2; tile++) {
    const int l = tile ? min(32 + m, L2 - 1) : m;
    const f16* abase = &h1w[l * H1S];
    f32x16 acc;
    #pragma unroll
    for (int i = 0; i < 16; i++) acc[i] = 0.0f;
    #pragma unroll
    for (int kc = 0; kc < 8; kc++) {
      const int e = (kc >> 1) * H1S + (kc & 1) * 16 + half * 8;
      const f16x8 a = *(const f16x8*)(abase + e);   // 16B-aligned single ds_read_b128
      acc = __builtin_amdgcn_mfma_f32_32x32x16_f16(a, bf2[kc], acc, 0, 0, 0);
    }
    if (tile == 0) {
      #pragma unroll
      for (int reg = 0; reg < 16; reg++) mx = fmaxf(mx, acc[reg]);   // rows 0..31 all valid
    } else if (half == 0) {
      mx = fmaxf(mx, fmaxf(acc[0], acc[1]));                         // rows 32,33
    }
  }
  mx = fmaxf(mx, __shfl_xor(mx, 32, 64));   // merge half-row-sets: lanes now hold channel-(m) max
  const float sv = selu_f(mx + b2v);        // bias uniform over positions -> add after max
  if (half == 0) se_out[(size_t)seq * DCH + m] = (f16)sv;

  // ---- attention MLP: readlane-broadcast (VALU), both halves redundant ----
  {
    const float4* wt1 = (const float4*)aw1T;   // [d*32+c]
    float a = ab1[m];
    #pragma unroll
    for (int c4 = 0; c4 < 8; c4++) {
      const float4 w = wt1[m * 8 + c4];
      a = fmaf(lane_bcast(sv, c4 * 4 + 0), w.x, a);
      a = fmaf(lane_bcast(sv, c4 * 4 + 1), w.y, a);
      a = fmaf(lane_bcast(sv, c4 * 4 + 2), w.z, a);
      a = fmaf(lane_bcast(sv, c4 * 4 + 3), w.w, a);
    }
    const float av = selu_f(a);

    const float4* wt2 = (const float4*)aw2T;
    float a2 = ab2[m];
    #pragma unroll
    for (int c4 = 0; c4 < 8; c4++) {
      const float4 w = wt2[m * 8 + c4];
      a2 = fmaf(lane_bcast(av, c4 * 4 + 0), w.x, a2);
      a2 = fmaf(lane_bcast(av, c4 * 4 + 1), w.y, a2);
      a2 = fmaf(lane_bcast(av, c4 * 4 + 2), w.z, a2);
      a2 = fmaf(lane_bcast(av, c4 * 4 + 3), w.w, a2);
    }
    float p = selu_f(a2) * aw3[m];
    #pragma unroll
    for (int off = 16; off > 0; off >>= 1) p += __shfl_xor(p, off, 32);
    if (lane == 0) sc_out[seq] = p + ab3[0];
  }
}

// ---- kernel 2: per-bag softmax pooling + output MLPs (se f16) ----
__global__ __launch_bounds__(256) void bag_kernel(
    const f16* __restrict__ se, const float* __restrict__ sc,
    const float* __restrict__ aw1, const float* __restrict__ ab1,
    const float* __restrict__ aw2, const float* __restrict__ ab2,
    const float* __restrict__ bw1, const float* __restrict__ bb1,
    const float* __restrict__ bw2, const float* __restrict__ bb2,
    float* __restrict__ out)
{
  const int bag = blockIdx.x, tid = threadIdx.x;
  const size_t base = (size_t)bag * SPB;

  __shared__ float pr[4][33];
  __shared__ float red[33];
  __shared__ float pool[DCH], hA[DCH], hB[DCH];

  float m = -3.4e38f;
  for (int i = tid; i < SPB; i += 256) m = fmaxf(m, sc[base + i]);
  #pragma unroll
  for (int off = 32; off > 0; off >>= 1) m = fmaxf(m, __shfl_xor(m, off, 64));
  if ((tid & 63) == 0) pr[tid >> 6][0] = m;
  __syncthreads();
  const float bagmax = fmaxf(fmaxf(pr[0][0], pr[1][0]), fmaxf(pr[2][0], pr[3][0]));
  __syncthreads();

  float acc[33];
  #pragma unroll
  for (int d = 0; d < 33; d++) acc[d] = 0.0f;
  for (int i = tid; i < SPB; i += 256) {
    const float e = __expf(sc[base + i] - bagmax);
    acc[32] += e;
    const f16* sr = &se[(base + i) * DCH];
    #pragma unroll
    for (int q = 0; q < 8; q++) {
      const f16x4 v = *(const f16x4*)(sr + q * 4);
      #pragma unroll
      for (int j = 0; j < 4; j++) acc[q * 4 + j] = fmaf(e, (float)v[j], acc[q * 4 + j]);
    }
  }
  #pragma unroll
  for (int d = 0; d < 33; d++) {
    float v = acc[d];
    #pragma unroll
    for (int off = 32; off > 0; off >>= 1) v += __shfl_xor(v, off, 64);
    if ((tid & 63) == 0) pr[tid >> 6][d] = v;
  }
  __syncthreads();
  if (tid < 33) red[tid] = pr[0][tid] + pr[1][tid] + pr[2][tid] + pr[3][tid];
  __syncthreads();
  if (tid < DCH) pool[tid] = red[tid] / red[32];
  __syncthreads();

  if (tid < DCH) {
    float a = ab1[tid], b = bb1[tid];
    #pragma unroll
    for (int c = 0; c < DCH; c++) {
      a = fmaf(pool[c], aw1[c * DCH + tid], a);
      b = fmaf(pool[c], bw1[c * DCH + tid], b);
    }
    hA[tid] = selu_f(a);
    hB[tid] = selu_f(b);
  }
  __syncthreads();

  if (tid < 21) {
    float v = ab2[tid];
    #pragma unroll
    for (int d = 0; d < DCH; d++) v = fmaf(hA[d], aw2[d * 21 + tid], v);
    out[bag * 21 + tid] = 1.0f / (1.0f + __expf(-v));
  } else if (tid >= 32 && tid < 72) {
    const int j = tid - 32;
    float v = bb2[j];
    #pragma unroll
    for (int d = 0; d < DCH; d++) v = fmaf(hB[d], bw2[d * 40 + j], v);
    out[N_BAGS * 21 + bag * 40 + j] = 1.0f / (1.0f + __expf(-v));
  }
}

extern "C" void kernel_launch(void* const* d_in, const int* in_sizes, int n_in,
                              void* d_out, int out_size, void* d_ws, size_t ws_size,
                              hipStream_t stream)
{
  const float* x    = (const float*)d_in[0];
  const float* c1w  = (const float*)d_in[2];
  const float* c1b  = (const float*)d_in[3];
  const float* c2w  = (const float*)d_in[4];
  const float* c2b  = (const float*)d_in[5];
  const float* aw1  = (const float*)d_in[6];
  const float* ab1  = (const float*)d_in[7];
  const float* aw2  = (const float*)d_in[8];
  const float* ab2  = (const float*)d_in[9];
  const float* aw3  = (const float*)d_in[10];
  const float* ab3  = (const float*)d_in[11];
  const float* oaw1 = (const float*)d_in[12];
  const float* oab1 = (const float*)d_in[13];
  const float* oaw2 = (const float*)d_in[14];
  const float* oab2 = (const float*)d_in[15];
  const float* obw1 = (const float*)d_in[16];
  const float* obb1 = (const float*)d_in[17];
  const float* obw2 = (const float*)d_in[18];
  const float* obb2 = (const float*)d_in[19];
  float* out = (float*)d_out;

  // ws layout: seh f16 (16 MB) | sc f32 (1 MB) | w1T/w2T f16 | aw1T/aw2T f32
  char* ws = (char*)d_ws;
  f16*   seh  = (f16*)ws;                                   // 8,000,000 f16
  float* sc   = (float*)(ws + (size_t)16000000);            // 250,000 f32
  f16*   w1T  = (f16*)(ws + (size_t)17000000);              // 2560 f16
  f16*   w2T  = w1T + 2560 + 2560;                          // 16B-aligned; 4096 f16
  float* aw1T = (float*)(ws + (size_t)17000000 + 32768);    // 1024 f32
  float* aw2T = aw1T + 1024;

  prep_kernel<<<1, 256, 0, stream>>>(c1w, c2w, aw1, aw2, w1T, w2T, aw1T, aw2T);
  seq_kernel<<<N_SEQ / WPB, NTHR, 0, stream>>>(x, w1T, c1b, w2T, c2b,
                                               aw1T, ab1, aw2T, ab2, aw3, ab3,
                                               seh, sc);
  bag_kernel<<<N_BAGS, 256, 0, stream>>>(seh, sc, oaw1, oab1, oaw2, oab2,
                                         obw1, obb1, obw2, obb2, out);
}